// Round 1
// baseline (4290.739 us; speedup 1.0000x reference)
//
#include <hip/hip_runtime.h>
#include <math.h>

// Problem constants (ExpertChoiceRouter: B=8, S=4096, D=4096, H=D/4=1024)
constexpr int BB = 8;
constexpr int S  = 4096;
constexpr int D  = 4096;
constexpr int H  = 1024;
constexpr int M  = BB * S;      // 32768 rows
constexpr int BM = 64;
constexpr int BN = 64;
constexpr int BK = 32;
constexpr int NT = H / BN;      // 16 n-tiles
constexpr int MT = M / BM;      // 512 m-tiles

// ---------------------------------------------------------------------------
// Kernel A: fp32 tiled GEMM  h = X @ W1, epilogue fuses +b1, exact GELU, *W2,
// and a per-block reduction over the 64-wide n-slice.  Writes partial logits
// part[nt][m] so kernel B can reduce deterministically (no float atomics).
// ---------------------------------------------------------------------------
__global__ __launch_bounds__(256) void gemm_router(
    const float* __restrict__ X,   // [M, D]
    const float* __restrict__ W1,  // [D, H]
    const float* __restrict__ b1,  // [H]
    const float* __restrict__ W2,  // [H]
    float* __restrict__ part)      // [NT, M]
{
    __shared__ float As[BM * 33];      // 64 x 32, padded stride 33
    __shared__ float Bs[BK * BN];      // 32 x 64
    __shared__ float red[BM][17];      // n-reduction scratch

    // XCD swizzle: keep the 16 n-tiles sharing an X m-stripe on one XCD.
    // blocks dispatch round-robin over 8 XCDs by blockIdx, so fix b%8 per
    // m-tile group: mt = (j>>4)*8 + xcd, nt = j&15  (bijective over 8192).
    int b   = blockIdx.x;
    int xcd = b & 7;
    int j   = b >> 3;
    int nt  = j & 15;
    int mt  = (j >> 4) * 8 + xcd;
    int m0  = mt * BM;
    int n0  = nt * BN;

    int tid = threadIdx.x;
    int tx  = tid & 15;    // n-direction, 16 threads
    int ty  = tid >> 4;    // m-direction, 16 threads

    float acc[4][4] = {};

    for (int kt = 0; kt < D; kt += BK) {
        // Load A tile 64x32 (two float4 per thread, coalesced along k)
        #pragma unroll
        for (int r = 0; r < 2; ++r) {
            int i   = tid + r * 256;       // 0..511
            int row = i >> 3;              // 0..63
            int c4  = (i & 7) * 4;         // 0..28
            float4 v = *reinterpret_cast<const float4*>(
                &X[(size_t)(m0 + row) * D + kt + c4]);
            As[row * 33 + c4 + 0] = v.x;
            As[row * 33 + c4 + 1] = v.y;
            As[row * 33 + c4 + 2] = v.z;
            As[row * 33 + c4 + 3] = v.w;
        }
        // Load B tile 32x64 (two float4 per thread, coalesced along n)
        #pragma unroll
        for (int r = 0; r < 2; ++r) {
            int i   = tid + r * 256;
            int row = i >> 4;              // 0..31
            int c4  = (i & 15) * 4;        // 0..60
            float4 v = *reinterpret_cast<const float4*>(
                &W1[(size_t)(kt + row) * H + n0 + c4]);
            *reinterpret_cast<float4*>(&Bs[row * BN + c4]) = v;
        }
        __syncthreads();

        #pragma unroll
        for (int kk = 0; kk < BK; ++kk) {
            float a0 = As[(ty * 4 + 0) * 33 + kk];
            float a1 = As[(ty * 4 + 1) * 33 + kk];
            float a2 = As[(ty * 4 + 2) * 33 + kk];
            float a3 = As[(ty * 4 + 3) * 33 + kk];
            float4 bv = *reinterpret_cast<float4*>(&Bs[kk * BN + tx * 4]);
            acc[0][0] += a0 * bv.x; acc[0][1] += a0 * bv.y;
            acc[0][2] += a0 * bv.z; acc[0][3] += a0 * bv.w;
            acc[1][0] += a1 * bv.x; acc[1][1] += a1 * bv.y;
            acc[1][2] += a1 * bv.z; acc[1][3] += a1 * bv.w;
            acc[2][0] += a2 * bv.x; acc[2][1] += a2 * bv.y;
            acc[2][2] += a2 * bv.z; acc[2][3] += a2 * bv.w;
            acc[3][0] += a3 * bv.x; acc[3][1] += a3 * bv.y;
            acc[3][2] += a3 * bv.z; acc[3][3] += a3 * bv.w;
        }
        __syncthreads();
    }

    // Epilogue: +b1, exact GELU, * W2[n], partial-reduce over this n-slice.
    float w2v[4], b1v[4];
    #pragma unroll
    for (int jj = 0; jj < 4; ++jj) {
        w2v[jj] = W2[n0 + tx * 4 + jj];
        b1v[jj] = b1[n0 + tx * 4 + jj];
    }
    #pragma unroll
    for (int i = 0; i < 4; ++i) {
        float ssum = 0.f;
        #pragma unroll
        for (int jj = 0; jj < 4; ++jj) {
            float x = acc[i][jj] + b1v[jj];
            float g = 0.5f * x * (1.0f + erff(x * 0.70710678118654752f));
            ssum += g * w2v[jj];
        }
        red[ty * 4 + i][tx] = ssum;
    }
    __syncthreads();
    if (tid < 64) {
        float s = 0.f;
        #pragma unroll
        for (int t = 0; t < 16; ++t) s += red[tid][t];
        part[(size_t)nt * M + m0 + tid] = s;
    }
}

// ---------------------------------------------------------------------------
// Kernel B: per batch-row (8 blocks) — reduce partial logits, sigmoid,
// variable-k selection via binary search over float-bit ordering.
// ---------------------------------------------------------------------------
__global__ __launch_bounds__(256) void select_topk(
    const float* __restrict__ part,  // [NT, M]
    const int*   __restrict__ mask,  // [BB, S] int32 (0/1)
    const float* __restrict__ b2,    // [1]
    float*       __restrict__ out)   // [2, BB, S]: weights then mask
{
    __shared__ unsigned us[S];       // masked score bits (0 = inactive)
    __shared__ int      na_s, cnt_s, cgt_s, cge_s;
    __shared__ unsigned lo_s, hi_s;

    int brow = blockIdx.x;
    int tid  = threadIdx.x;

    if (tid == 0) na_s = 0;
    __syncthreads();

    float b2v = b2[0];
    int local_na = 0;
    for (int s = tid; s < S; s += 256) {
        float sum = 0.f;
        #pragma unroll
        for (int t = 0; t < NT; ++t) sum += part[t * M + brow * S + s];
        float logit = sum + b2v;
        float sc = 1.0f / (1.0f + expf(-logit));   // sigmoid, ALPHA=1
        int a = mask[brow * S + s];
        us[s] = a ? __float_as_uint(sc) : 0u;      // sc in (0,1): bits >= 1
        local_na += (a ? 1 : 0);
    }
    atomicAdd(&na_s, local_na);
    __syncthreads();

    int n_act = na_s;
    int k = (n_act >= 1) ? max(n_act >> 1, 1) : 0;  // floor(0.5*n), clip [1,n]

    unsigned T = 0;
    if (k > 0) {
        // binary search k-th largest bits: invariant count(>=lo)>=k, count(>=hi+1)<k
        if (tid == 0) { lo_s = 1u; hi_s = 0x3F800000u; }  // scores < 1.0
        __syncthreads();
        while (true) {
            unsigned lo = lo_s, hi = hi_s;
            if (lo >= hi) break;
            unsigned mid = lo + ((hi - lo + 1u) >> 1);
            int local = 0;
            for (int s = tid; s < S; s += 256) local += (us[s] >= mid) ? 1 : 0;
            if (tid == 0) cnt_s = 0;
            __syncthreads();
            #pragma unroll
            for (int off = 32; off > 0; off >>= 1)
                local += __shfl_down(local, off, 64);
            if ((tid & 63) == 0) atomicAdd(&cnt_s, local);
            __syncthreads();
            int c = cnt_s;
            if (tid == 0) { if (c >= k) lo_s = mid; else hi_s = mid - 1u; }
            __syncthreads();
        }
        T = lo_s;

        // tie handling (rare): reference stable-sort keeps lowest indices
        int lgt = 0, lge = 0;
        for (int s = tid; s < S; s += 256) {
            lgt += (us[s] > T) ? 1 : 0;
            lge += (us[s] >= T) ? 1 : 0;
        }
        if (tid == 0) { cgt_s = 0; cge_s = 0; }
        __syncthreads();
        #pragma unroll
        for (int off = 32; off > 0; off >>= 1) {
            lgt += __shfl_down(lgt, off, 64);
            lge += __shfl_down(lge, off, 64);
        }
        if ((tid & 63) == 0) { atomicAdd(&cgt_s, lgt); atomicAdd(&cge_s, lge); }
        __syncthreads();
        int c_gt = cgt_s, c_ge = cge_s;
        int need_eq = k - c_gt;          // >= 1 by search invariant
        if (c_ge - c_gt != need_eq) {    // duplicates straddle the cutoff
            if (tid == 0) {
                int taken = 0;
                for (int s = 0; s < S; ++s) {
                    if (us[s] == T) {
                        if (taken >= need_eq) us[s] = 0u;  // deselect
                        ++taken;
                    }
                }
            }
            __syncthreads();
        }
    }
    __syncthreads();

    for (int s = tid; s < S; s += 256) {
        bool sel = (k > 0) && (us[s] >= T);
        float sc = __uint_as_float(us[s]);
        out[brow * S + s]      = sel ? sc : 0.0f;    // router_weights
        out[M + brow * S + s]  = sel ? 1.0f : 0.0f;  // selected_mask
    }
}

// ---------------------------------------------------------------------------
extern "C" void kernel_launch(void* const* d_in, const int* in_sizes, int n_in,
                              void* d_out, int out_size, void* d_ws, size_t ws_size,
                              hipStream_t stream)
{
    const float* X    = (const float*)d_in[0];  // hidden_states [8,4096,4096]
    const int*   mask = (const int*)  d_in[1];  // active_mask   [8,4096]
    const float* W1   = (const float*)d_in[2];  // [4096,1024]
    const float* b1   = (const float*)d_in[3];  // [1024]
    const float* W2   = (const float*)d_in[4];  // [1024,1]
    const float* b2   = (const float*)d_in[5];  // [1]
    float* out  = (float*)d_out;                // [2, 8, 4096]
    float* part = (float*)d_ws;                 // [NT, M] = 2 MB scratch

    hipLaunchKernelGGL(gemm_router, dim3(MT * NT), dim3(256), 0, stream,
                       X, W1, b1, W2, part);
    hipLaunchKernelGGL(select_topk, dim3(BB), dim3(256), 0, stream,
                       part, mask, b2, out);
}

// Round 2
// 1679.158 us; speedup vs baseline: 2.5553x; 2.5553x over previous
//
#include <hip/hip_runtime.h>
#include <math.h>

typedef unsigned int u32;
typedef unsigned short u16;
typedef __attribute__((ext_vector_type(8))) short short8;
typedef __attribute__((ext_vector_type(4))) float f32x4;

// Problem constants (ExpertChoiceRouter: B=8, S=4096, D=4096, H=D/4=1024)
constexpr int BB = 8;
constexpr int S  = 4096;
constexpr int D  = 4096;
constexpr int H  = 1024;
constexpr int M  = BB * S;        // 32768 rows
constexpr int BM = 128;
constexpr int BN = 64;
constexpr int BK = 32;
constexpr int NT     = H / BN;    // 16 n-tiles
constexpr int MTILES = M / BM;    // 256 m-tiles
constexpr int KSTEPS = D / BK;    // 128

// d_ws layout:
//   part  : [NT][M] float          @ 0        (2 MB)
//   Bp_hi : [NT*KSTEPS][4][64][8] bf16 @ 2 MB  (8 MB)
//   Bp_lo : same                   @ 10 MB    (8 MB)

// --- split fp32 -> bf16 hi (truncate) + bf16 lo (residual, truncate) -------
__device__ inline void split_bf16(float x, u16& h, u16& l) {
    u32 u  = __float_as_uint(x);
    u32 hu = u & 0xFFFF0000u;
    h = (u16)(u >> 16);
    float r = x - __uint_as_float(hu);      // exact (Sterbenz)
    l = (u16)(__float_as_uint(r) >> 16);
}

__device__ inline f32x4 mfma16(short8 a, short8 b, f32x4 c) {
    return __builtin_amdgcn_mfma_f32_16x16x32_bf16(a, b, c, 0, 0, 0);
}

__device__ inline void gl_lds16(const u16* g, u16* l) {
    __builtin_amdgcn_global_load_lds(
        (const __attribute__((address_space(1))) u32*)g,
        (__attribute__((address_space(3))) u32*)l, 16, 0, 0);
}

// ---------------------------------------------------------------------------
// Pack W1 (fp32 [D][H]) -> Bp_hi/Bp_lo bf16 in MFMA B-fragment order:
// Bp[nt*128+ks][k8][n][j] = W1[ks*32+k8*8+j][nt*64+n]  (j contiguous => b128 frag)
// ---------------------------------------------------------------------------
__global__ __launch_bounds__(256) void pack_w1(
    const float* __restrict__ W1, u16* __restrict__ bh, u16* __restrict__ bl)
{
    int blk = blockIdx.x;              // nt*128 + ks
    int nt = blk >> 7, ks = blk & 127;
    int t  = threadIdx.x;
    int k8 = t >> 6, n = t & 63;
    int kbase = ks * 32 + k8 * 8;

    short8 vh, vl;
    #pragma unroll
    for (int j = 0; j < 8; ++j) {
        float x = W1[(size_t)(kbase + j) * H + nt * 64 + n];
        u16 hh, ll;
        split_bf16(x, hh, ll);
        vh[j] = (short)hh;
        vl[j] = (short)ll;
    }
    size_t base = (size_t)blk * 2048 + k8 * 512 + n * 8;
    *reinterpret_cast<short8*>(bh + base) = vh;
    *reinterpret_cast<short8*>(bl + base) = vl;
}

// ---------------------------------------------------------------------------
// MFMA GEMM: h = X @ W1 via 3-mult bf16 split, fused +b1 / GELU / *W2 epilogue
// writing per-n-tile partial logits part[nt][m].
// A fragments: registers (lane-local load + split).  B: global_load_lds.
// ---------------------------------------------------------------------------
__global__ __launch_bounds__(256) void gemm_mfma(
    const float* __restrict__ X,
    const u16*   __restrict__ Bph, const u16* __restrict__ Bpl,
    const float* __restrict__ b1,  const float* __restrict__ W2,
    float*       __restrict__ part)
{
    __shared__ u16 Bh[4 * 64 * 8];   // [k8][n][8]  4 KB
    __shared__ u16 Bl[4 * 64 * 8];

    // XCD swizzle: 16 n-tiles of one m-stripe land on one XCD (X read ~once).
    int b   = blockIdx.x;
    int xcd = b & 7;
    int j   = b >> 3;
    int nt  = j & 15;
    int mtg = j >> 4;
    int mt  = mtg * 8 + xcd;
    int m0  = mt * BM;
    int n0  = nt * BN;

    int tid  = threadIdx.x;
    int lane = tid & 63, wv = tid >> 6;
    int li   = lane & 15, quad = lane >> 4;

    // A pointers: lane loads rows m0 + wv*32 + mtl*16 + li, k = ks*32 + quad*8 ..
    const float* aptr0 = X + (size_t)(m0 + wv * 32 +  0 + li) * D + quad * 8;
    const float* aptr1 = X + (size_t)(m0 + wv * 32 + 16 + li) * D + quad * 8;

    // B staging assignment: waves 0,1 -> hi halves; waves 2,3 -> lo halves
    const u16* gsrc  = (wv < 2) ? Bph : Bpl;
    u16*       lbase = ((wv < 2) ? Bh : Bl) + (wv & 1) * 1024;

    f32x4 acc[2][4] = {};

    for (int ks = 0; ks < KSTEPS; ++ks) {
        // ---- B: global -> LDS (2 x 16B per lane) ----
        const u16* g0 = gsrc + (size_t)(nt * 128 + ks) * 2048 + (wv & 1) * 1024 + lane * 8;
        gl_lds16(g0,       lbase + lane * 8);
        gl_lds16(g0 + 512, lbase + 512 + lane * 8);

        // ---- A: raw fp32 loads (overlap with LDS DMA) ----
        f32x4 a0lo = *(const f32x4*)(aptr0);
        f32x4 a0hi = *(const f32x4*)(aptr0 + 4);
        f32x4 a1lo = *(const f32x4*)(aptr1);
        f32x4 a1hi = *(const f32x4*)(aptr1 + 4);
        aptr0 += BK; aptr1 += BK;

        __syncthreads();   // drains vmcnt: B tile visible, A regs ready

        // ---- split A to bf16 hi/lo fragments ----
        short8 ah[2], al[2];
        #pragma unroll
        for (int e = 0; e < 4; ++e) {
            u16 h, l;
            split_bf16(a0lo[e], h, l); ah[0][e]     = (short)h; al[0][e]     = (short)l;
            split_bf16(a0hi[e], h, l); ah[0][e + 4] = (short)h; al[0][e + 4] = (short)l;
            split_bf16(a1lo[e], h, l); ah[1][e]     = (short)h; al[1][e]     = (short)l;
            split_bf16(a1hi[e], h, l); ah[1][e + 4] = (short)h; al[1][e + 4] = (short)l;
        }

        // ---- MFMA: 4 n-tiles x 2 m-tiles x 3 mults ----
        #pragma unroll
        for (int ntl = 0; ntl < 4; ++ntl) {
            int off = (quad * 64 + ntl * 16 + li) * 8;
            short8 bhf = *reinterpret_cast<const short8*>(Bh + off);
            short8 blf = *reinterpret_cast<const short8*>(Bl + off);
            #pragma unroll
            for (int mtl = 0; mtl < 2; ++mtl) {
                acc[mtl][ntl] = mfma16(ah[mtl], bhf, acc[mtl][ntl]);
                acc[mtl][ntl] = mfma16(al[mtl], bhf, acc[mtl][ntl]);
                acc[mtl][ntl] = mfma16(ah[mtl], blf, acc[mtl][ntl]);
            }
        }
        __syncthreads();   // before next step's staging overwrites B
    }

    // ---- epilogue: +b1, exact GELU, *W2, reduce over this 64-wide n-slice ----
    float b1v[4], w2v[4];
    #pragma unroll
    for (int ntl = 0; ntl < 4; ++ntl) {
        b1v[ntl] = b1[n0 + ntl * 16 + li];
        w2v[ntl] = W2[n0 + ntl * 16 + li];
    }
    #pragma unroll
    for (int mtl = 0; mtl < 2; ++mtl) {
        #pragma unroll
        for (int r = 0; r < 4; ++r) {
            float s = 0.f;
            #pragma unroll
            for (int ntl = 0; ntl < 4; ++ntl) {
                float x = acc[mtl][ntl][r] + b1v[ntl];
                float g = 0.5f * x * (1.0f + erff(x * 0.70710678118654752f));
                s += g * w2v[ntl];
            }
            // reduce across the 16 lanes (li) of this quad
            s += __shfl_xor(s, 1, 64);
            s += __shfl_xor(s, 2, 64);
            s += __shfl_xor(s, 4, 64);
            s += __shfl_xor(s, 8, 64);
            if (li == 0) {
                int row = m0 + wv * 32 + mtl * 16 + quad * 4 + r;
                part[(size_t)nt * M + row] = s;
            }
        }
    }
}

// ---------------------------------------------------------------------------
// Kernel B: per batch-row — reduce partials, sigmoid, variable-k selection
// via binary search over float-bit ordering.  (unchanged from round 1)
// ---------------------------------------------------------------------------
__global__ __launch_bounds__(256) void select_topk(
    const float* __restrict__ part,  // [NT, M]
    const int*   __restrict__ mask,  // [BB, S] int32 (0/1)
    const float* __restrict__ b2,    // [1]
    float*       __restrict__ out)   // [2, BB, S]: weights then mask
{
    __shared__ unsigned us[S];
    __shared__ int      na_s, cnt_s, cgt_s, cge_s;
    __shared__ unsigned lo_s, hi_s;

    int brow = blockIdx.x;
    int tid  = threadIdx.x;

    if (tid == 0) na_s = 0;
    __syncthreads();

    float b2v = b2[0];
    int local_na = 0;
    for (int s = tid; s < S; s += 256) {
        float sum = 0.f;
        #pragma unroll
        for (int t = 0; t < NT; ++t) sum += part[t * M + brow * S + s];
        float logit = sum + b2v;
        float sc = 1.0f / (1.0f + expf(-logit));
        int a = mask[brow * S + s];
        us[s] = a ? __float_as_uint(sc) : 0u;
        local_na += (a ? 1 : 0);
    }
    atomicAdd(&na_s, local_na);
    __syncthreads();

    int n_act = na_s;
    int k = (n_act >= 1) ? max(n_act >> 1, 1) : 0;

    unsigned T = 0;
    if (k > 0) {
        if (tid == 0) { lo_s = 1u; hi_s = 0x3F800000u; }
        __syncthreads();
        while (true) {
            unsigned lo = lo_s, hi = hi_s;
            if (lo >= hi) break;
            unsigned mid = lo + ((hi - lo + 1u) >> 1);
            int local = 0;
            for (int s = tid; s < S; s += 256) local += (us[s] >= mid) ? 1 : 0;
            if (tid == 0) cnt_s = 0;
            __syncthreads();
            #pragma unroll
            for (int off = 32; off > 0; off >>= 1)
                local += __shfl_down(local, off, 64);
            if ((tid & 63) == 0) atomicAdd(&cnt_s, local);
            __syncthreads();
            int c = cnt_s;
            if (tid == 0) { if (c >= k) lo_s = mid; else hi_s = mid - 1u; }
            __syncthreads();
        }
        T = lo_s;

        int lgt = 0, lge = 0;
        for (int s = tid; s < S; s += 256) {
            lgt += (us[s] > T) ? 1 : 0;
            lge += (us[s] >= T) ? 1 : 0;
        }
        if (tid == 0) { cgt_s = 0; cge_s = 0; }
        __syncthreads();
        #pragma unroll
        for (int off = 32; off > 0; off >>= 1) {
            lgt += __shfl_down(lgt, off, 64);
            lge += __shfl_down(lge, off, 64);
        }
        if ((tid & 63) == 0) { atomicAdd(&cgt_s, lgt); atomicAdd(&cge_s, lge); }
        __syncthreads();
        int c_gt = cgt_s, c_ge = cge_s;
        int need_eq = k - c_gt;
        if (c_ge - c_gt != need_eq) {
            if (tid == 0) {
                int taken = 0;
                for (int s = 0; s < S; ++s) {
                    if (us[s] == T) {
                        if (taken >= need_eq) us[s] = 0u;
                        ++taken;
                    }
                }
            }
            __syncthreads();
        }
    }
    __syncthreads();

    for (int s = tid; s < S; s += 256) {
        bool sel = (k > 0) && (us[s] >= T);
        float sc = __uint_as_float(us[s]);
        out[brow * S + s]     = sel ? sc : 0.0f;
        out[M + brow * S + s] = sel ? 1.0f : 0.0f;
    }
}

// ---------------------------------------------------------------------------
extern "C" void kernel_launch(void* const* d_in, const int* in_sizes, int n_in,
                              void* d_out, int out_size, void* d_ws, size_t ws_size,
                              hipStream_t stream)
{
    const float* X    = (const float*)d_in[0];  // hidden_states [8,4096,4096]
    const int*   mask = (const int*)  d_in[1];  // active_mask   [8,4096]
    const float* W1   = (const float*)d_in[2];  // [4096,1024]
    const float* b1   = (const float*)d_in[3];  // [1024]
    const float* W2   = (const float*)d_in[4];  // [1024,1]
    const float* b2   = (const float*)d_in[5];  // [1]
    float* out  = (float*)d_out;                // [2, 8, 4096]

    float* part = (float*)d_ws;                           // 2 MB
    u16*   Bph  = (u16*)((char*)d_ws + (2u  << 20));      // 8 MB
    u16*   Bpl  = (u16*)((char*)d_ws + (10u << 20));      // 8 MB

    hipLaunchKernelGGL(pack_w1,   dim3(NT * KSTEPS),   dim3(256), 0, stream, W1, Bph, Bpl);
    hipLaunchKernelGGL(gemm_mfma, dim3(MTILES * NT),   dim3(256), 0, stream,
                       X, Bph, Bpl, b1, W2, part);
    hipLaunchKernelGGL(select_topk, dim3(BB), dim3(256), 0, stream, part, mask, b2, out);
}